// Round 11
// baseline (152.495 us; speedup 1.0000x reference)
//
#include <hip/hip_runtime.h>
#include <math.h>

// AnnealingTopKSoftMax: per-row top-8 mask + softmax over 512-wide rows.
// One wave (64 lanes) per row-group; lane l owns elements [8l, 8l+8).
//
// R11 = R10's per-row pipeline (byte-identical math), restructured so each
// wave processes ROWS_PER_WAVE=4 consecutive rows with a distance-1 load
// prefetch: row i+1's two dwordx4 loads are issued before row i's compute,
// hiding HBM latency under the ~450-cycle selection chain. Only row 0's
// load latency remains exposed (amortized 4x).
//
// Per-row selection (R9/R10-proven exact):
//  - lane-local descending sort (Batcher, 19 CE)
//  - 8 pop-all-equal extraction rounds (DPP-tree wave max; SALU multiplicity
//    clamp; triangular pop-shift) -> exact top-8 multiset M, T, S
//  - mask x>=T via cndmask; rare duplicate-at-boundary fixup zeroes
//    highest-index copies of T (jax.lax.top_k keeps lowest indices).

#define DEPTH 512
#define RPW 4   // rows per wave

typedef float f32x4 __attribute__((ext_vector_type(4)));
typedef unsigned long long u64;

#define CE(arr, i, j)                         \
    do {                                      \
        float _hi = fmaxf(arr[i], arr[j]);    \
        float _lo = fminf(arr[i], arr[j]);    \
        arr[i] = _hi;                         \
        arr[j] = _lo;                         \
    } while (0)

template <int CTRL>
__device__ __forceinline__ float dpp_max_step(float v) {
    int vi = __float_as_int(v);
    int sh = __builtin_amdgcn_update_dpp(vi, vi, CTRL, 0xF, 0xF, false);
    return fmaxf(v, __int_as_float(sh));
}

// wave-wide max of 64 lanes, returned as wave-uniform scalar
__device__ __forceinline__ float wave_max64(float v) {
    v = dpp_max_step<0x111>(v);  // row_shr:1
    v = dpp_max_step<0x112>(v);  // row_shr:2
    v = dpp_max_step<0x114>(v);  // row_shr:4
    v = dpp_max_step<0x118>(v);  // row_shr:8
    v = dpp_max_step<0x142>(v);  // row_bcast:15
    v = dpp_max_step<0x143>(v);  // row_bcast:31 -> lane63 = full max
    return __int_as_float(__builtin_amdgcn_readlane(__float_as_int(v), 63));
}

// R10-verified per-row pipeline: x[8] -> masked softmax in o0,o1
__device__ __forceinline__ void process_row(const float x[8], int lane,
                                            f32x4& o0, f32x4& o1) {
    // lane-local descending sort (Batcher, 19 CE)
    float v[8] = {x[0], x[1], x[2], x[3], x[4], x[5], x[6], x[7]};
    CE(v, 0, 1); CE(v, 2, 3); CE(v, 4, 5); CE(v, 6, 7);
    CE(v, 0, 2); CE(v, 1, 3); CE(v, 4, 6); CE(v, 5, 7);
    CE(v, 1, 2); CE(v, 5, 6);
    CE(v, 0, 4); CE(v, 1, 5); CE(v, 2, 6); CE(v, 3, 7);
    CE(v, 2, 4); CE(v, 3, 5);
    CE(v, 1, 2); CE(v, 3, 4); CE(v, 5, 6);

    // 8 pop-all-equal extraction rounds (triangular shift)
    float M = 0.0f, S = 0.0f, T = 0.0f;
    int cum = 0;

#pragma unroll
    for (int r = 0; r < 8; ++r) {
        const float m = wave_max64(v[0]);
        const bool eq = (v[0] == m);
        const int c = __popcll(__ballot(eq));

        int kk = 8 - cum;
        kk = (kk < 0) ? 0 : kk;
        kk = (c < kk) ? c : kk;
        const bool crossed = (cum < 8) && (cum + c >= 8);
        T = crossed ? m : T;
        cum += c;

        if (r == 0) { M = m; S = (float)kk; }       // exp(0)=1
        else        { S = fmaf((float)kk, __expf(m - M), S); }

        if (r < 7) {
#pragma unroll
            for (int k = 0; k < 7; ++k)
                if (k <= 6 - r) v[k] = eq ? v[k + 1] : v[k];
        }
    }

    // output: mask = (x >= T) directly as cndmask operand
    const float inv = __builtin_amdgcn_rcpf(S);
    float o[8];
#pragma unroll
    for (int j = 0; j < 8; ++j) {
        const float e = __expf(x[j] - M) * inv;
        o[j] = (x[j] >= T) ? e : 0.0f;
    }

    // selected-count (uniform); ==8 in all non-degenerate rows
    int cnt = 0;
#pragma unroll
    for (int j = 0; j < 8; ++j) cnt += __popcll(__ballot(x[j] >= T));

    if (cnt > 8) {   // rare exact fixup: zero highest-index copies of T
        int extra = cnt - 8;
        unsigned eqm = 0u;
#pragma unroll
        for (int j = 0; j < 8; ++j) eqm |= (x[j] == T ? 1u : 0u) << j;
        for (int e = 0; e < extra; ++e) {
            const u64 ball = __ballot(eqm != 0u);
            const int L = 63 - __builtin_clzll(ball);
            if (lane == L) {
                const int j = 31 - __builtin_clz(eqm);
                o[j] = 0.0f;
                eqm &= ~(1u << j);
            }
        }
    }

#pragma unroll
    for (int j = 0; j < 4; ++j) { o0[j] = o[j]; o1[j] = o[j + 4]; }
}

__global__ __launch_bounds__(256, 8)
void AnnealingTopKSoftMax_kernel(const float* __restrict__ in,
                                 float* __restrict__ out) {
    const int wave = threadIdx.x >> 6;
    const int lane = threadIdx.x & 63;
    const int grp  = (blockIdx.x << 2) | wave;      // wave's row group

    const size_t base0 = (size_t)grp * (RPW * DEPTH) + (size_t)lane * 8;

    // prologue: load row 0
    const f32x4* p = reinterpret_cast<const f32x4*>(in + base0);
    f32x4 a = p[0];
    f32x4 b = p[1];

#pragma unroll
    for (int i = 0; i < RPW; ++i) {
        // prefetch row i+1 before computing row i
        f32x4 an, bn;
        if (i + 1 < RPW) {
            const f32x4* pn =
                reinterpret_cast<const f32x4*>(in + base0 + (size_t)(i + 1) * DEPTH);
            an = pn[0];
            bn = pn[1];
        }

        const float x[8] = {a[0], a[1], a[2], a[3], b[0], b[1], b[2], b[3]};
        f32x4 o0, o1;
        process_row(x, lane, o0, o1);

        f32x4* q = reinterpret_cast<f32x4*>(out + base0 + (size_t)i * DEPTH);
        __builtin_nontemporal_store(o0, q);
        __builtin_nontemporal_store(o1, q + 1);

        if (i + 1 < RPW) { a = an; b = bn; }
    }
}

extern "C" void kernel_launch(void* const* d_in, const int* in_sizes, int n_in,
                              void* d_out, int out_size, void* d_ws, size_t ws_size,
                              hipStream_t stream) {
    const float* in = (const float*)d_in[0];
    float* out = (float*)d_out;
    const int rows = in_sizes[0] / DEPTH;           // 131072
    const int blocks = rows / (4 * RPW);            // 4 waves/block x RPW rows/wave
    AnnealingTopKSoftMax_kernel<<<blocks, 256, 0, stream>>>(in, out);
}